// Round 6
// baseline (213.366 us; speedup 1.0000x reference)
//
#include <hip/hip_runtime.h>
#include <cstdint>
#include <cstddef>

// Problem constants (fixed by the reference)
#define N_ROWS 4096
#define DIM    512
#define NCLS   30000
#define BM 256
#define BN 256
#define BK 64
#define NT2  118                    // ceil(30000/256) N-tiles
#define CPAD (NT2 * 256)            // 30208, padded classes (zero rows)
#define SPT 2                       // N-tiles per block strip
#define NSTRIPS (NT2 / SPT)         // 59
#define KT  (DIM / BK)              // 8 K-tiles per N-tile
#define NS  (SPT * KT)              // 16 K-tiles per block

typedef float  f32x4  __attribute__((ext_vector_type(4)));
typedef short  bf16x8 __attribute__((ext_vector_type(8)));
typedef unsigned int   u32;
typedef unsigned short u16;

// ---- workspace layout (bytes) ----
#define WB_BYTES   ((size_t)CPAD * DIM * 2)     // 30,932,992
#define EB_BYTES   ((size_t)N_ROWS * DIM * 2)   //  4,194,304
#define PS_BYTES   ((size_t)NT2 * N_ROWS * 4)   //  1,933,312
#define CT_BYTES   ((size_t)N_ROWS * 4)
#define BL_BYTES   (64 * 4)
#define LAB_BYTES  ((size_t)N_ROWS * 4)

#define CLIP_HI ( 1.0f - 1e-7f)
#define CLIP_LO (-1.0f + 1e-7f)
#define COSM 0.8775825618903728f    // cos(0.5)
#define SINM 0.4794255386042030f    // sin(0.5)
#define K1   92.33248261972189f     // 64*log2(e): exp(64c-64) = 2^((c-1)*K1)

__device__ __forceinline__ u16 f2bf(float f) {  // RNE float->bf16
  u32 x = __builtin_bit_cast(u32, f);
  x += 0x7fffu + ((x >> 16) & 1u);
  return (u16)(x >> 16);
}

__device__ __forceinline__ void gl_lds16(const u16* g, u16* l) {
  __builtin_amdgcn_global_load_lds((const __attribute__((address_space(1))) u32*)g,
                                   (__attribute__((address_space(3))) u32*)l,
                                   16, 0, 0);
}

// ---- label dtype probe: int64 little-endian reads as [lo,0,lo,0,...] ----
__global__ void lab_detect(const int* __restrict__ lab, int* __restrict__ flag) {
  __shared__ int s_nz;
  int tid = threadIdx.x;
  if (tid == 0) s_nz = 0;
  __syncthreads();
  int nz = 0;
  for (int i = tid; i < N_ROWS / 2; i += 1024) nz |= lab[2 * i + 1];
  if (nz) atomicOr(&s_nz, 1);
  __syncthreads();
  if (tid == 0) *flag = (s_nz == 0) ? 1 : 0;   // 1 -> int64 layout
}

__global__ void lab_fix(const int* __restrict__ lab, const int* __restrict__ flag,
                        int* __restrict__ out) {
  int i = blockIdx.x * 256 + threadIdx.x;
  out[i] = flag[0] ? lab[2 * i] : lab[i];
}

// ---- W: L2-normalize rows + cast bf16; pad rows [NCLS,CPAD) with zeros ----
__global__ void prep_w(const float* __restrict__ w, u16* __restrict__ wb) {
  int wv   = threadIdx.x >> 6;
  int lane = threadIdx.x & 63;
  int c = blockIdx.x * 4 + wv;              // one wave per class row
  u16* dst = wb + (size_t)c * DIM + lane * 8;
  if (c >= NCLS) {
    *(uint4*)dst = make_uint4(0, 0, 0, 0);
    return;
  }
  const float* src = w + (size_t)c * DIM + lane * 8;
  float4 v0 = *(const float4*)src;
  float4 v1 = *(const float4*)(src + 4);
  float a[8] = {v0.x, v0.y, v0.z, v0.w, v1.x, v1.y, v1.z, v1.w};
  float ss = 0.f;
  #pragma unroll
  for (int i = 0; i < 8; i++) ss += a[i] * a[i];
  #pragma unroll
  for (int off = 32; off; off >>= 1) ss += __shfl_xor(ss, off, 64);
  float inv = 1.0f / fmaxf(sqrtf(ss), 1e-12f);
  union { u16 h[8]; uint4 q; } pk;
  #pragma unroll
  for (int i = 0; i < 8; i++) pk.h[i] = f2bf(a[i] * inv);
  *(uint4*)dst = pk.q;
}

// ---- E: cast bf16 ----
__global__ void prep_e(const float* __restrict__ e, u16* __restrict__ eb) {
  size_t idx = ((size_t)blockIdx.x * 256 + threadIdx.x) * 8;
  float4 v0 = *(const float4*)(e + idx);
  float4 v1 = *(const float4*)(e + idx + 4);
  float a[8] = {v0.x, v0.y, v0.z, v0.w, v1.x, v1.y, v1.z, v1.w};
  union { u16 h[8]; uint4 q; } pk;
  #pragma unroll
  for (int i = 0; i < 8; i++) pk.h[i] = f2bf(a[i]);
  *(uint4*)(eb + idx) = pk.q;
}

// ---- target cosine per row, f32: dot(emb[n], w[lab[n]]/||w[lab[n]]||) ----
__global__ void tgt_k(const float* __restrict__ emb, const float* __restrict__ wts,
                      const int* __restrict__ lab, float* __restrict__ ct) {
  int w = threadIdx.x >> 6, l = threadIdx.x & 63;
  int row = blockIdx.x * 4 + w;
  int c = lab[row];
  const float* e  = emb + (size_t)row * DIM + l * 8;
  const float* wp = wts + (size_t)c   * DIM + l * 8;
  float4 e0 = *(const float4*)e,       e1 = *(const float4*)(e + 4);
  float4 w0 = *(const float4*)wp,      w1 = *(const float4*)(wp + 4);
  float dot = e0.x*w0.x + e0.y*w0.y + e0.z*w0.z + e0.w*w0.w
            + e1.x*w1.x + e1.y*w1.y + e1.z*w1.z + e1.w*w1.w;
  float ss  = w0.x*w0.x + w0.y*w0.y + w0.z*w0.z + w0.w*w0.w
            + w1.x*w1.x + w1.y*w1.y + w1.z*w1.z + w1.w*w1.w;
  #pragma unroll
  for (int off = 32; off; off >>= 1) {
    dot += __shfl_xor(dot, off, 64);
    ss  += __shfl_xor(ss,  off, 64);
  }
  if (l == 0) ct[row] = dot / fmaxf(sqrtf(ss), 1e-12f);
}

// ---- fused GEMM + clip + partial sum-exp (fixed max = 64), 256x256 tile ----
// m201-style 8-phase schedule at BK=64: 2-buffer dbuf (128 KB), 4 phases per
// K-tile, each {ds_reads + 2 gl_lds stage chunks; s_barrier; lgkmcnt(0);
// setprio(1) 16 MFMA setprio(0); s_barrier}; vmcnt(0)+barrier only at the
// K-tile boundary (staged chunks are 1-4 phases old by then).
__global__ __launch_bounds__(512, 1) void arc_main(
    const u16* __restrict__ eb, const u16* __restrict__ wb,
    float* __restrict__ psum)
{
  __shared__ __align__(16) u16 lds[2][2][BM * BK];   // [buf][A,B][256*64] = 128 KB
  __shared__ float ep[4][BM];
  const int t   = threadIdx.x;
  const int l   = t & 63;
  const int w   = t >> 6;
  const int wm  = w >> 2, wn = w & 3;
  const int cl  = l & 15, bq = l >> 4;
  const int mi    = blockIdx.x & 15;    // m inner: concurrent blocks share E in L3
  const int strip = blockIdx.x >> 4;
  const int rowbase = mi * BM;
  const int n0s = strip * SPT;

  // frag LDS elem offsets; 16B-slot swizzle slot' = slot ^ (r&7)
  // (quarter-wave cl 0-7 -> 8 distinct slots = 32 banks; cl 8-15 repeat = free)
  u32 aoff[16], boff[8];
  #pragma unroll
  for (int s = 0; s < 2; s++) {
    #pragma unroll
    for (int m = 0; m < 8; m++) {
      int r = wm * 128 + m * 16 + cl;
      aoff[s * 8 + m] = (u32)r * BK + (((s * 4 + bq) ^ (r & 7)) << 3);
    }
    #pragma unroll
    for (int n = 0; n < 4; n++) {
      int r = wn * 64 + n * 16 + cl;
      boff[s * 4 + n] = (u32)r * BK + (((s * 4 + bq) ^ (r & 7)) << 3);
    }
  }

  // staging: one 8 KB chunk (64 rows x 128 B) per gl_lds round over 512 thr;
  // linear LDS dest + inverse-swizzled global source (same involution).
  u32 goff[4];
  #pragma unroll
  for (int c = 0; c < 4; c++) {
    int rl = c * 64 + (t >> 3);
    goff[c] = (u32)rl * DIM + (((t & 7) ^ (rl & 7)) << 3);
  }
  const u16* ebR = eb + (size_t)rowbase * DIM;

  f32x4 acc[8][4];
  #pragma unroll
  for (int m = 0; m < 8; m++)
    #pragma unroll
    for (int n = 0; n < 4; n++)
      #pragma unroll
      for (int q = 0; q < 4; q++) acc[m][n][q] = 0.f;

  // prologue: stage K-tile 0 (k0 = 0, n-tile n0s) into buf 0
  {
    const u32 bb0 = (u32)n0s * (BN * DIM);
    #pragma unroll
    for (int c = 0; c < 4; c++) {
      gl_lds16(ebR + goff[c],       &lds[0][0][c * 4096 + w * 512]);
      gl_lds16(wb + bb0 + goff[c],  &lds[0][1][c * 4096 + w * 512]);
    }
  }

  for (int u = 0; u < NS; u++) {
    const int bi = u & 1;
    const u16* As = &lds[bi][0][0];
    const u16* Bs = &lds[bi][1][0];
    u16* An = &lds[bi ^ 1][0][0];
    u16* Bn = &lds[bi ^ 1][1][0];
    const bool st = (u + 1 < NS);
    const u32 k0n = (u32)(((u + 1) & 7) * BK);
    const u32 bbn = (u32)(n0s + ((u + 1) >> 3)) * (BN * DIM);

    asm volatile("s_waitcnt vmcnt(0)" ::: "memory");  // tile u's 8 chunks landed
    __builtin_amdgcn_s_barrier();                     // ..for ALL waves
    asm volatile("" ::: "memory");

    bf16x8 a0, a1, a2, a3, b0, b1, b2, b3;

    // ---- phase 0: read a[m0-3]k0 + b[n0-3]k0; stage A0,B0(u+1); MFMA m0-3 k0
    a0 = *(const bf16x8*)&As[aoff[0]];  a1 = *(const bf16x8*)&As[aoff[1]];
    a2 = *(const bf16x8*)&As[aoff[2]];  a3 = *(const bf16x8*)&As[aoff[3]];
    b0 = *(const bf16x8*)&Bs[boff[0]];  b1 = *(const bf16x8*)&Bs[boff[1]];
    b2 = *(const bf16x8*)&Bs[boff[2]];  b3 = *(const bf16x8*)&Bs[boff[3]];
    if (st) {
      gl_lds16(ebR + k0n + goff[0],      An + w * 512);
      gl_lds16(wb + bbn + k0n + goff[0], Bn + w * 512);
    }
    __builtin_amdgcn_s_barrier();
    asm volatile("s_waitcnt lgkmcnt(0)" ::: "memory");
    __builtin_amdgcn_s_setprio(1);
    acc[0][0] = __builtin_amdgcn_mfma_f32_16x16x32_bf16(a0, b0, acc[0][0], 0, 0, 0);
    acc[0][1] = __builtin_amdgcn_mfma_f32_16x16x32_bf16(a0, b1, acc[0][1], 0, 0, 0);
    acc[0][2] = __builtin_amdgcn_mfma_f32_16x16x32_bf16(a0, b2, acc[0][2], 0, 0, 0);
    acc[0][3] = __builtin_amdgcn_mfma_f32_16x16x32_bf16(a0, b3, acc[0][3], 0, 0, 0);
    acc[1][0] = __builtin_amdgcn_mfma_f32_16x16x32_bf16(a1, b0, acc[1][0], 0, 0, 0);
    acc[1][1] = __builtin_amdgcn_mfma_f32_16x16x32_bf16(a1, b1, acc[1][1], 0, 0, 0);
    acc[1][2] = __builtin_amdgcn_mfma_f32_16x16x32_bf16(a1, b2, acc[1][2], 0, 0, 0);
    acc[1][3] = __builtin_amdgcn_mfma_f32_16x16x32_bf16(a1, b3, acc[1][3], 0, 0, 0);
    acc[2][0] = __builtin_amdgcn_mfma_f32_16x16x32_bf16(a2, b0, acc[2][0], 0, 0, 0);
    acc[2][1] = __builtin_amdgcn_mfma_f32_16x16x32_bf16(a2, b1, acc[2][1], 0, 0, 0);
    acc[2][2] = __builtin_amdgcn_mfma_f32_16x16x32_bf16(a2, b2, acc[2][2], 0, 0, 0);
    acc[2][3] = __builtin_amdgcn_mfma_f32_16x16x32_bf16(a2, b3, acc[2][3], 0, 0, 0);
    acc[3][0] = __builtin_amdgcn_mfma_f32_16x16x32_bf16(a3, b0, acc[3][0], 0, 0, 0);
    acc[3][1] = __builtin_amdgcn_mfma_f32_16x16x32_bf16(a3, b1, acc[3][1], 0, 0, 0);
    acc[3][2] = __builtin_amdgcn_mfma_f32_16x16x32_bf16(a3, b2, acc[3][2], 0, 0, 0);
    acc[3][3] = __builtin_amdgcn_mfma_f32_16x16x32_bf16(a3, b3, acc[3][3], 0, 0, 0);
    __builtin_amdgcn_s_setprio(0);
    __builtin_amdgcn_s_barrier();

    // ---- phase 1: read a[m4-7]k0; stage A1,B1(u+1); MFMA m4-7 k0 ----
    a0 = *(const bf16x8*)&As[aoff[4]];  a1 = *(const bf16x8*)&As[aoff[5]];
    a2 = *(const bf16x8*)&As[aoff[6]];  a3 = *(const bf16x8*)&As[aoff[7]];
    if (st) {
      gl_lds16(ebR + k0n + goff[1],      An + 4096 + w * 512);
      gl_lds16(wb + bbn + k0n + goff[1], Bn + 4096 + w * 512);
    }
    __builtin_amdgcn_s_barrier();
    asm volatile("s_waitcnt lgkmcnt(0)" ::: "memory");
    __builtin_amdgcn_s_setprio(1);
    acc[4][0] = __builtin_amdgcn_mfma_f32_16x16x32_bf16(a0, b0, acc[4][0], 0, 0, 0);
    acc[4][1] = __builtin_amdgcn_mfma_f32_16x16x32_bf16(a0, b1, acc[4][1], 0, 0, 0);
    acc[4][2] = __builtin_amdgcn_mfma_f32_16x16x32_bf16(a0, b2, acc[4][2], 0, 0, 0);
    acc[4][3] = __builtin_amdgcn_mfma_f32_16x16x32_bf16(a0, b3, acc[4][3], 0, 0, 0);
    acc[5][0] = __builtin_amdgcn_mfma_f32_16x16x32_bf16(a1, b0, acc[5][0], 0, 0, 0);
    acc[5][1] = __builtin_amdgcn_mfma_f32_16x16x32_bf16(a1, b1, acc[5][1], 0, 0, 0);
    acc[5][2] = __builtin_amdgcn_mfma_f32_16x16x32_bf16(a1, b2, acc[5][2], 0, 0, 0);
    acc[5][3] = __builtin_amdgcn_mfma_f32_16x16x32_bf16(a1, b3, acc[5][3], 0, 0, 0);
    acc[6][0] = __builtin_amdgcn_mfma_f32_16x16x32_bf16(a2, b0, acc[6][0], 0, 0, 0);
    acc[6][1] = __builtin_amdgcn_mfma_f32_16x16x32_bf16(a2, b1, acc[6][1], 0, 0, 0);
    acc[6][2] = __builtin_amdgcn_mfma_f32_16x16x32_bf16(a2, b2, acc[6][2], 0, 0, 0);
    acc[6][3] = __builtin_amdgcn_mfma_f32_16x16x32_bf16(a2, b3, acc[6][3], 0, 0, 0);
    acc[7][0] = __builtin_amdgcn_mfma_f32_16x16x32_bf16(a3, b0, acc[7][0], 0, 0, 0);
    acc[7][1] = __builtin_amdgcn_mfma_f32_16x16x32_bf16(a3, b1, acc[7][1], 0, 0, 0);
    acc[7][2] = __builtin_amdgcn_mfma_f32_16x16x32_bf16(a3, b2, acc[7][2], 0, 0, 0);
    acc[7][3] = __builtin_amdgcn_mfma_f32_16x16x32_bf16(a3, b3, acc[7][3], 0, 0, 0);
    __builtin_amdgcn_s_setprio(0);
    __builtin_amdgcn_s_barrier();

    // ---- phase 2: read a[m0-3]k1 + b[n0-3]k1; stage A2,B2(u+1); MFMA m0-3 k1
    a0 = *(const bf16x8*)&As[aoff[8]];  a1 = *(const bf16x8*)&As[aoff[9]];
    a2 = *(const bf16x8*)&As[aoff[10]]; a3 = *(const bf16x8*)&As[aoff[11]];
    b0 = *(const bf16x8*)&Bs[boff[4]];  b1 = *(const bf16x8*)&Bs[boff[5]];
    b2 = *(const bf16x8*)&Bs[boff[6]];  b3 = *(const bf16x8*)&Bs[boff[7]];
    if (st) {
      gl_lds16(ebR + k0n + goff[2],      An + 8192 + w * 512);
      gl_lds16(wb + bbn + k0n + goff[2], Bn + 8192 + w * 512);
    }
    __builtin_amdgcn_s_barrier();
    asm volatile("s_waitcnt lgkmcnt(0)" ::: "memory");
    __builtin_amdgcn_s_setprio(1);
    acc[0][0] = __builtin_amdgcn_mfma_f32_16x16x32_bf16(a0, b0, acc[0][0], 0, 0, 0);
    acc[0][1] = __builtin_amdgcn_mfma_f32_16x16x32_bf16(a0, b1, acc[0][1], 0, 0, 0);
    acc[0][2] = __builtin_amdgcn_mfma_f32_16x16x32_bf16(a0, b2, acc[0][2], 0, 0, 0);
    acc[0][3] = __builtin_amdgcn_mfma_f32_16x16x32_bf16(a0, b3, acc[0][3], 0, 0, 0);
    acc[1][0] = __builtin_amdgcn_mfma_f32_16x16x32_bf16(a1, b0, acc[1][0], 0, 0, 0);
    acc[1][1] = __builtin_amdgcn_mfma_f32_16x16x32_bf16(a1, b1, acc[1][1], 0, 0, 0);
    acc[1][2] = __builtin_amdgcn_mfma_f32_16x16x32_bf16(a1, b2, acc[1][2], 0, 0, 0);
    acc[1][3] = __builtin_amdgcn_mfma_f32_16x16x32_bf16(a1, b3, acc[1][3], 0, 0, 0);
    acc[2][0] = __builtin_amdgcn_mfma_f32_16x16x32_bf16(a2, b0, acc[2][0], 0, 0, 0);
    acc[2][1] = __builtin_amdgcn_mfma_f32_16x16x32_bf16(a2, b1, acc[2][1], 0, 0, 0);
    acc[2][2] = __builtin_amdgcn_mfma_f32_16x16x32_bf16(a2, b2, acc[2][2], 0, 0, 0);
    acc[2][3] = __builtin_amdgcn_mfma_f32_16x16x32_bf16(a2, b3, acc[2][3], 0, 0, 0);
    acc[3][0] = __builtin_amdgcn_mfma_f32_16x16x32_bf16(a3, b0, acc[3][0], 0, 0, 0);
    acc[3][1] = __builtin_amdgcn_mfma_f32_16x16x32_bf16(a3, b1, acc[3][1], 0, 0, 0);
    acc[3][2] = __builtin_amdgcn_mfma_f32_16x16x32_bf16(a3, b2, acc[3][2], 0, 0, 0);
    acc[3][3] = __builtin_amdgcn_mfma_f32_16x16x32_bf16(a3, b3, acc[3][3], 0, 0, 0);
    __builtin_amdgcn_s_setprio(0);
    __builtin_amdgcn_s_barrier();

    // ---- phase 3: read a[m4-7]k1; stage A3,B3(u+1); MFMA m4-7 k1 ----
    a0 = *(const bf16x8*)&As[aoff[12]]; a1 = *(const bf16x8*)&As[aoff[13]];
    a2 = *(const bf16x8*)&As[aoff[14]]; a3 = *(const bf16x8*)&As[aoff[15]];
    if (st) {
      gl_lds16(ebR + k0n + goff[3],      An + 12288 + w * 512);
      gl_lds16(wb + bbn + k0n + goff[3], Bn + 12288 + w * 512);
    }
    __builtin_amdgcn_s_barrier();
    asm volatile("s_waitcnt lgkmcnt(0)" ::: "memory");
    __builtin_amdgcn_s_setprio(1);
    acc[4][0] = __builtin_amdgcn_mfma_f32_16x16x32_bf16(a0, b0, acc[4][0], 0, 0, 0);
    acc[4][1] = __builtin_amdgcn_mfma_f32_16x16x32_bf16(a0, b1, acc[4][1], 0, 0, 0);
    acc[4][2] = __builtin_amdgcn_mfma_f32_16x16x32_bf16(a0, b2, acc[4][2], 0, 0, 0);
    acc[4][3] = __builtin_amdgcn_mfma_f32_16x16x32_bf16(a0, b3, acc[4][3], 0, 0, 0);
    acc[5][0] = __builtin_amdgcn_mfma_f32_16x16x32_bf16(a1, b0, acc[5][0], 0, 0, 0);
    acc[5][1] = __builtin_amdgcn_mfma_f32_16x16x32_bf16(a1, b1, acc[5][1], 0, 0, 0);
    acc[5][2] = __builtin_amdgcn_mfma_f32_16x16x32_bf16(a1, b2, acc[5][2], 0, 0, 0);
    acc[5][3] = __builtin_amdgcn_mfma_f32_16x16x32_bf16(a1, b3, acc[5][3], 0, 0, 0);
    acc[6][0] = __builtin_amdgcn_mfma_f32_16x16x32_bf16(a2, b0, acc[6][0], 0, 0, 0);
    acc[6][1] = __builtin_amdgcn_mfma_f32_16x16x32_bf16(a2, b1, acc[6][1], 0, 0, 0);
    acc[6][2] = __builtin_amdgcn_mfma_f32_16x16x32_bf16(a2, b2, acc[6][2], 0, 0, 0);
    acc[6][3] = __builtin_amdgcn_mfma_f32_16x16x32_bf16(a2, b3, acc[6][3], 0, 0, 0);
    acc[7][0] = __builtin_amdgcn_mfma_f32_16x16x32_bf16(a3, b0, acc[7][0], 0, 0, 0);
    acc[7][1] = __builtin_amdgcn_mfma_f32_16x16x32_bf16(a3, b1, acc[7][1], 0, 0, 0);
    acc[7][2] = __builtin_amdgcn_mfma_f32_16x16x32_bf16(a3, b2, acc[7][2], 0, 0, 0);
    acc[7][3] = __builtin_amdgcn_mfma_f32_16x16x32_bf16(a3, b3, acc[7][3], 0, 0, 0);
    __builtin_amdgcn_s_setprio(0);
    __builtin_amdgcn_s_barrier();

    if ((u & 7) == 7) {
      // epilogue for N-tile nt: clip, exp2, sum over wave's 64 cols,
      // cross-wn merge via LDS, one psum row-partial per N-tile.
      const int nt = n0s + (u >> 3);
      #pragma unroll
      for (int m = 0; m < 8; m++) {
        #pragma unroll
        for (int q = 0; q < 4; q++) {
          float s = 0.f;
          #pragma unroll
          for (int n = 0; n < 4; n++) {
            float tc = __builtin_amdgcn_fmed3f(acc[m][n][q], CLIP_LO, CLIP_HI);
            s += __builtin_amdgcn_exp2f(__builtin_fmaf(tc, K1, -K1));
            acc[m][n][q] = 0.f;
          }
          s += __shfl_xor(s, 1, 64);
          s += __shfl_xor(s, 2, 64);
          s += __shfl_xor(s, 4, 64);
          s += __shfl_xor(s, 8, 64);
          if ((l & 15) == 0) ep[wn][wm * 128 + m * 16 + (l >> 4) * 4 + q] = s;
        }
      }
      asm volatile("s_waitcnt lgkmcnt(0)" ::: "memory");
      __builtin_amdgcn_s_barrier();
      asm volatile("" ::: "memory");
      if (l < 32) {
        int r = w * 32 + l;
        float v = ep[0][r] + ep[1][r] + ep[2][r] + ep[3][r];
        psum[(size_t)nt * N_ROWS + rowbase + r] = v;
      }
      __builtin_amdgcn_s_barrier();   // ep reads done before next tile's writes
    }
  }
}

// ---- per-row LSE merge + margin swap + per-block loss sums ----
__global__ void arc_finish1(const float* __restrict__ psum, const float* __restrict__ ct,
                            float* __restrict__ bl) {
  int tid = threadIdx.x;
  int row = blockIdx.x * 256 + tid;
  float S = 0.f;
  for (int p = 0; p < NT2; p++) S += psum[(size_t)p * N_ROWS + row];
  float c  = __builtin_amdgcn_fmed3f(ct[row], CLIP_LO, CLIP_HI);
  float cm = c * COSM - sqrtf(fmaxf(1.0f - c * c, 0.0f)) * SINM;
  // swap the target's no-margin term for the margin term (both vs fixed max 64)
  float S2 = S - __builtin_amdgcn_exp2f(__builtin_fmaf(c,  K1, -K1))
               + __builtin_amdgcn_exp2f(__builtin_fmaf(cm, K1, -K1));
  float loss = 64.0f + __builtin_amdgcn_logf(S2) * 0.6931471805599453f - 64.0f * cm;
  #pragma unroll
  for (int off = 32; off; off >>= 1) loss += __shfl_xor(loss, off, 64);
  __shared__ float red[4];
  if ((tid & 63) == 0) red[tid >> 6] = loss;
  __syncthreads();
  if (tid == 0) bl[blockIdx.x] = red[0] + red[1] + red[2] + red[3];
}

__global__ void arc_finish2(const float* __restrict__ bl, float* __restrict__ out) {
  if (threadIdx.x == 0) {
    float t = 0.f;
    for (int i = 0; i < N_ROWS / 256; i++) t += bl[i];
    out[0] = t * (1.0f / (float)N_ROWS);
  }
}

extern "C" void kernel_launch(void* const* d_in, const int* in_sizes, int n_in,
                              void* d_out, int out_size, void* d_ws, size_t ws_size,
                              hipStream_t stream) {
  const float* emb   = (const float*)d_in[0];
  const int*   lab   = (const int*)d_in[1];
  const float* wts   = (const float*)d_in[2];

  char* ws = (char*)d_ws;
  u16*   wb    = (u16*)(ws);
  u16*   eb    = (u16*)(ws + WB_BYTES);
  float* psum  = (float*)(ws + WB_BYTES + EB_BYTES);
  float* ct    = (float*)(ws + WB_BYTES + EB_BYTES + PS_BYTES);
  float* bl    = (float*)(ws + WB_BYTES + EB_BYTES + PS_BYTES + CT_BYTES);
  int*   lab32 = (int*)  (ws + WB_BYTES + EB_BYTES + PS_BYTES + CT_BYTES + BL_BYTES);
  int*   flag  = (int*)  (ws + WB_BYTES + EB_BYTES + PS_BYTES + CT_BYTES + BL_BYTES + LAB_BYTES);
  // total ~37.1 MiB of d_ws assumed available

  lab_detect<<<dim3(1), dim3(1024), 0, stream>>>(lab, flag);
  lab_fix<<<dim3(N_ROWS / 256), dim3(256), 0, stream>>>(lab, flag, lab32);
  prep_w<<<dim3(CPAD / 4), dim3(256), 0, stream>>>(wts, wb);
  prep_e<<<dim3((N_ROWS * DIM / 8) / 256), dim3(256), 0, stream>>>(emb, eb);
  tgt_k<<<dim3(N_ROWS / 4), dim3(256), 0, stream>>>(emb, wts, lab32, ct);
  arc_main<<<dim3(16 * NSTRIPS), dim3(512), 0, stream>>>(eb, wb, psum);
  arc_finish1<<<dim3(N_ROWS / 256), dim3(256), 0, stream>>>(psum, ct, bl);
  arc_finish2<<<dim3(1), dim3(64), 0, stream>>>(bl, (float*)d_out);
}